// Round 10
// baseline (167.789 us; speedup 1.0000x reference)
//
#include <hip/hip_runtime.h>
#include <math.h>

static __device__ __forceinline__ float frcp(float x){ return __builtin_amdgcn_rcpf(x); }
static __device__ __forceinline__ float fsq (float x){ return __builtin_amdgcn_sqrtf(x); }
static __device__ __forceinline__ float rld(float x, int l){
  return __uint_as_float(__builtin_amdgcn_readlane(__float_as_uint(x), l));
}

// ---- quad (4-lane) butterfly reductions via quad_perm DPP; result in all 4 lanes ----
template<int CTRL>
static __device__ __forceinline__ float qaddd(float x){
  int t = __builtin_amdgcn_update_dpp(0, __float_as_int(x), CTRL, 0xf, 0xf, true);
  return x + __int_as_float(t);
}
template<int CTRL>
static __device__ __forceinline__ float qmaxd(float x){
  int t = __builtin_amdgcn_update_dpp(__float_as_int(x), __float_as_int(x), CTRL, 0xf, 0xf, false);
  return fmaxf(x, __int_as_float(t));
}
template<int CTRL>
static __device__ __forceinline__ float qmind(float x){
  int t = __builtin_amdgcn_update_dpp(__float_as_int(x), __float_as_int(x), CTRL, 0xf, 0xf, false);
  return fminf(x, __int_as_float(t));
}
// 0xB1 = quad_perm[1,0,3,2], 0x4E = quad_perm[2,3,0,1]
static __device__ __forceinline__ float qsum(float x){ return qaddd<0x4E>(qaddd<0xB1>(x)); }
static __device__ __forceinline__ float qmax(float x){ return qmaxd<0x4E>(qmaxd<0xB1>(x)); }
static __device__ __forceinline__ float qmin(float x){ return qmind<0x4E>(qmind<0xB1>(x)); }

// ---- wave64 sum (6-step DPP), total on lane 63 (for LayerNorm in kernel B) ----
template<int CTRL, int RM>
static __device__ __forceinline__ float dppadd(float x){
  int t = __builtin_amdgcn_update_dpp(0, __float_as_int(x), CTRL, RM, 0xf, true);
  return x + __int_as_float(t);
}
static __device__ __forceinline__ float wsum63(float x){
  x = dppadd<0x111,0xf>(x); x = dppadd<0x112,0xf>(x);
  x = dppadd<0x114,0xf>(x); x = dppadd<0x118,0xf>(x);
  x = dppadd<0x142,0xa>(x); x = dppadd<0x143,0xc>(x);
  return x;
}

__global__ void transpose_w(const float* __restrict__ W, float* __restrict__ Wt){
  int idx = blockIdx.x * 256 + threadIdx.x;
  if (idx < 60 * 48) { int f = idx / 48, j = idx - f * 48; Wt[j * 60 + f] = W[idx]; }
}

// ================= Kernel A: per-trajectory 60-feature extraction =================
// 4 threads per trajectory; thread p owns rows [12p, 12p+12), deltas [12p,12p+12),
// cos indices [12p, 12p+12). Serial walk, quad-combine, p==0 writes feats.
__global__ __launch_bounds__(256)
void feat_kernel(const float* __restrict__ coords,
                 const int* __restrict__ lengths,
                 float* __restrict__ feats, int B)
{
  const int t    = blockIdx.x * 256 + threadIdx.x;
  const int traj = t >> 2;
  const int p    = t & 3;
  if (traj >= B) return;

  const int n = lengths[traj];          // quad-uniform
  const int m = n - 1;                  // 3..47
  const int half = m >> 1;
  const float* cp = coords + (size_t)traj * 480;
  float* fb = feats + (size_t)traj * 60;
  const int base = p * 12;

  // first owned row
  float prev[10];
  {
    const float2* pp = reinterpret_cast<const float2*>(cp + base * 10);
#pragma unroll
    for (int k = 0; k < 5; ++k){ float2 v = pp[k]; prev[2*k]=v.x; prev[2*k+1]=v.y; }
  }

  float d_prev[10];
#pragma unroll
  for (int k = 0; k < 10; ++k) d_prev[k] = 0.f;
  float inv_prev = 0.f;

  float path=0.f, dm2=0.f, mxdm=0.f, sf=0.f, ss=0.f, uu=0.f;
  float scos=0.f, scos2=0.f, sng=0.f, csl=0.f, cs2=0.f;
  float mxc=-INFINITY, mnc=INFINITY;
  float uk[10];
#pragma unroll
  for (int k = 0; k < 10; ++k) uk[k] = 0.f;

#pragma unroll
  for (int dj = 0; dj < 13; ++dj) {
    const int j = base + dj;

    // coord stats for row j (owned rows only)
    if (dj < 12 && j < n) {
      float t1 = 0.f, t2 = 0.f;
#pragma unroll
      for (int k = 0; k < 10; ++k) { t1 += prev[k]; t2 = fmaf(prev[k], prev[k], t2); }
      csl += t1; cs2 += t2;
    }

    // next row (clamped; clamped rows only feed masked deltas)
    const int rn = (j + 1 < 47) ? (j + 1) : 47;
    float nx[10];
    {
      const float2* pp = reinterpret_cast<const float2*>(cp + rn * 10);
#pragma unroll
      for (int k = 0; k < 5; ++k){ float2 v = pp[k]; nx[2*k]=v.x; nx[2*k+1]=v.y; }
    }

    // delta j and dot with previous delta
    float d[10]; float dsq = 0.f, dot = 0.f;
#pragma unroll
    for (int k = 0; k < 10; ++k) {
      float a = nx[k] - prev[k];
      d[k] = a;
      dsq = fmaf(a, a, dsq);
      dot = fmaf(d_prev[k], a, dot);
    }
    const float sn  = (dsq > 0.f) ? fsq(fmaxf(dsq, 1e-30f)) : 0.f;  // safe_norm
    const float inv = frcp(fmaxf(sn, 1e-8f));                       // 1/na (COS_EPS)

    // owned delta accumulation
    if (dj < 12) {
      const bool act = j < m;
      const float dm = act ? sn : 0.f;
      path += dm;
      dm2  += act ? dsq : 0.f;
      mxdm  = fmaxf(mxdm, dm);
      sf   += (j <= half) ? dm : 0.f;
      ss   += (j >= half) ? dm : 0.f;      // j<m via dm
      const float im = act ? inv : 0.f;
#pragma unroll
      for (int k = 0; k < 10; ++k) uk[k] = fmaf(d[k], im, uk[k]);
      uu = fmaf(dsq * im, im, uu);
      if (p == 0 && dj < 3) {              // padded_deltas rows 0..2 (m>=3 always)
#pragma unroll
        for (int k = 0; k < 10; ++k) fb[21 + dj * 10 + k] = d[k];
      }
    }

    // owned cos index jc = j-1
    if (dj >= 1) {
      const int jc = j - 1;
      const bool ca = jc < (n - 2);
      const float cosv = dot * inv_prev * inv;
      const float cm = ca ? cosv : 0.f;
      scos  += cm;
      scos2  = fmaf(cm, cm, scos2);
      mxc    = fmaxf(mxc, ca ? cosv : -INFINITY);
      mnc    = fminf(mnc, ca ? cosv :  INFINITY);
      sng   += (ca && cosv < 0.f) ? 1.f : 0.f;
      if (p == 0 && dj <= 9) fb[51 + jc] = ca ? (1.f - cosv) : 0.f;  // padded_curvs
    }

#pragma unroll
    for (int k = 0; k < 10; ++k) { prev[k] = nx[k]; d_prev[k] = d[k]; }
    inv_prev = inv;
  }

  // total displacement: owner of row m computes ||row_m - row_0||^2
  float tq = 0.f;
  if (m >= base && m < base + 12) {
    const float2* p0 = reinterpret_cast<const float2*>(cp);
    const float2* pm = reinterpret_cast<const float2*>(cp + m * 10);
#pragma unroll
    for (int k = 0; k < 5; ++k) {
      float2 a = p0[k], z = pm[k];
      float dx = z.x - a.x, dy = z.y - a.y;
      tq = fmaf(dx, dx, fmaf(dy, dy, tq));
    }
  }

  // ---- quad combines (results in all 4 lanes) ----
  path = qsum(path);  dm2 = qsum(dm2);   mxdm = qmax(mxdm);
  sf   = qsum(sf);    ss  = qsum(ss);    uu   = qsum(uu);
  scos = qsum(scos);  scos2 = qsum(scos2); sng = qsum(sng);
  mxc  = qmax(mxc);   mnc = qmin(mnc);
  csl  = qsum(csl);   cs2 = qsum(cs2);   tq   = qsum(tq);
  float Usq = 0.f;
#pragma unroll
  for (int k = 0; k < 10; ++k) { float Uk = qsum(uk[k]); Usq = fmaf(Uk, Uk, Usq); }

  // ---- scalar features ----
  const float EPSf = 1e-9f;
  const float nf = (float)n, mf = (float)m, ncf = (float)(n - 2);
  const float rncf = frcp(ncf);
  const float total_disp = (tq > 0.f) ? fsq(fmaxf(tq, 1e-30f)) : 0.f;
  const float disp_ratio = total_disp * frcp(path + EPSf);
  const float mean_cv = (ncf - scos) * rncf;
  const float sum_cv2 = fmaf(-2.f, scos, ncf) + scos2;
  const float cv_var  = (sum_cv2 - ncf * mean_cv * mean_cv) * frcp(fmaxf(ncf - 1.f, 1.f));
  const float std_cv  = fsq(fmaxf(cv_var, 1e-30f));
  const float fh = sf * frcp((float)(half + 1));
  const float sh = ss * frcp((float)(m - half));
  const float conv = (fh - sh) * frcp(fh + EPSf);
  const float npairs = mf * (mf - 1.f) * 0.5f;
  const float par = (Usq - uu) * 0.5f * frcp(fmaxf(npairs, 1.f));
  const float mean_dm = path * frcp(mf);
  const float dm_var = (dm2 - mf * mean_dm * mean_dm) * frcp(mf - 1.f);
  const float std_dm = fsq(fmaxf(dm_var, 1e-30f));
  const float jump = (mean_dm > EPSf) ? mxdm * frcp(mean_dm) : 1.f;
  const float cnt = nf * 10.f;
  const float mean_co = csl * frcp(cnt);
  const float co_var = (cs2 - cnt * mean_co * mean_co) * frcp(cnt - 1.f);
  const float std_co = fsq(fmaxf(co_var, 1e-30f));

  if (p == 0) {
    fb[0]  = total_disp;
    fb[1]  = path;
    fb[2]  = disp_ratio;
    fb[3]  = nf * 0.1f;
    fb[4]  = mean_cv;
    fb[5]  = 1.f - mnc;          // max_curv
    fb[6]  = std_cv;
    fb[7]  = mxc - mnc;          // curv_range
    fb[8]  = scos * rncf;        // mean_cos
    fb[9]  = mnc;                // min_cos
    fb[10] = sng * rncf;         // dir_changes
    fb[11] = disp_ratio;         // linearity
    fb[12] = 1.f - disp_ratio;   // loop_score
    fb[13] = conv;
    fb[14] = par;
    fb[15] = jump;
    fb[16] = -conv;              // cascade
    fb[17] = mean_dm;
    fb[18] = std_dm;
    fb[19] = mean_co;
    fb[20] = std_co;
  }
}

// ================= Kernel B: h = feat@W + b, LayerNorm, GELU =================
__global__ __launch_bounds__(256)
void mlp_kernel(const float* __restrict__ feats,
                const float* __restrict__ Wt,    // [48][60]
                const float* __restrict__ bias,
                const float* __restrict__ lnw,
                const float* __restrict__ lnb,
                float* __restrict__ out, int B)
{
  const int lane = threadIdx.x & 63;
  const int b = blockIdx.x * 4 + (threadIdx.x >> 6);
  if (b >= B) return;

  const float* fp = feats + (size_t)b * 60;
  float f[60];
#pragma unroll
  for (int q = 0; q < 15; ++q) {
    float4 v = reinterpret_cast<const float4*>(fp)[q];   // uniform address
    f[4*q] = v.x; f[4*q+1] = v.y; f[4*q+2] = v.z; f[4*q+3] = v.w;
  }

  const int jc = (lane < 48) ? lane : 47;
  float h = bias[jc];
  const float4* wr = reinterpret_cast<const float4*>(Wt + jc * 60);
#pragma unroll
  for (int q = 0; q < 15; ++q) {
    float4 w = wr[q];
    h = fmaf(f[4*q+0], w.x, h);
    h = fmaf(f[4*q+1], w.y, h);
    h = fmaf(f[4*q+2], w.z, h);
    h = fmaf(f[4*q+3], w.w, h);
  }

  const float hm = (lane < 48) ? h : 0.f;
  const float s1 = rld(wsum63(hm), 63);
  const float s2 = rld(wsum63(hm * hm), 63);
  const float mu  = s1 * (1.f / 48.f);
  const float var = fmaf(-mu, mu, s2 * (1.f / 48.f));
  const float rstd = __builtin_amdgcn_rsqf(var + 1e-5f);

  if (lane < 48) {
    float x = (h - mu) * rstd * lnw[lane] + lnb[lane];
    float x2 = x * x;
    float u  = 0.7978845608f * x * fmaf(0.044715f, x2, 1.f);
    float e  = __builtin_amdgcn_exp2f(u * 2.885390082f);   // e^{2u}
    float th = fmaf(-2.f, frcp(1.f + e), 1.f);
    out[(size_t)b * 48 + lane] = 0.5f * x * (1.f + th);
  }
}

extern "C" void kernel_launch(void* const* d_in, const int* in_sizes, int n_in,
                              void* d_out, int out_size, void* d_ws, size_t ws_size,
                              hipStream_t stream)
{
  const float* coords = (const float*)d_in[0];
  const int*   lengths= (const int*)d_in[1];
  const float* W      = (const float*)d_in[2];
  const float* bias   = (const float*)d_in[3];
  const float* lnw    = (const float*)d_in[4];
  const float* lnb    = (const float*)d_in[5];
  float* out = (float*)d_out;

  const int B = in_sizes[1];
  const size_t need = (size_t)(2880 + (size_t)B * 60) * sizeof(float);

  if (ws_size >= need) {
    float* Wt    = (float*)d_ws;
    float* feats = (float*)d_ws + 2880;
    transpose_w<<<12, 256, 0, stream>>>(W, Wt);
    feat_kernel<<<(B * 4 + 255) / 256, 256, 0, stream>>>(coords, lengths, feats, B);
    mlp_kernel<<<(B + 3) / 4, 256, 0, stream>>>(feats, Wt, bias, lnw, lnb, out, B);
  } else {
    // minimal fallback: feats in first part of ws is impossible; run mlp on
    // features computed directly into out is not possible either — require ws.
    // Observed ws_size is ~256 MB, so this path is never expected; guard with
    // a degenerate launch that still produces correct results via kernel A+B
    // packed at the start of out is unsafe, so just use whatever ws we have:
    float* Wt    = (float*)d_ws;                  // 11.5 KB
    float* feats = (float*)d_ws + 2880;           // will fault only if ws truly tiny
    transpose_w<<<12, 256, 0, stream>>>(W, Wt);
    feat_kernel<<<(B * 4 + 255) / 256, 256, 0, stream>>>(coords, lengths, feats, B);
    mlp_kernel<<<(B + 3) / 4, 256, 0, stream>>>(feats, Wt, bias, lnw, lnb, out, B);
  }
}